// Round 14
// baseline (173.543 us; speedup 1.0000x reference)
//
#include <hip/hip_runtime.h>
#include <hip/hip_fp16.h>
#include <math.h>

#define B_ 4
#define N_ 250000
#define K_ 32
#define NB 4096    // fine buckets: (bits(qc) >> 19); nonneg floats -> <= 4080
#define NB2 2048   // coarse neg-table buckets: (bits >> 20)
#define HCH 16     // hist chunks over N  (N_/16 = 15625 exact)
#define S2 16      // pass2 chunks over N (R8 shape: best measured)
#define SC 4       // segstats chunks per seg
#define SLOT_SHIFT 13  // 8192 entries per seg in list

// ws layout: small accums @0 (8KB), p05 @8192, emb2 @65536 (8MB half4),
// hneg_g @65536+8MB (2MB, zeroed inside k_emb), tabN next (2MB, NOT zeroed:
// scanpos/pass2neg both skip Gf<=0 segs), list next (4MB)
//
// Ledger of hard-won facts:
// R14/R15: NO device-scope fences/atomics in hot kernels (L1/L2 poisoning).
// R16: hist KG=4 packed-16bit counters: neutral-to-worse (but loads proved
//   NOT the hist bottleneck — enables R27's KG=1).
// R17 (keeper): XCD-clustered block decode (batch -> XCD pair -> 2MB emb2
//   L2-resident). hist/pass2neg/scanpos.
// R18: segstats-into-emb fusion REGRESSED. k_segstats itself is ~0-3us.
// R19+R22+R23+R24 (MLP MECHANISM): latency-bound kernels gain from PER-WAVE
//   MLP, not occupancy; gain scales with uncovered latency (low TLP = big).
// R20 (keeper): branch-free predicated seed load in k_emb.
// R25 (keeper, -13.7us): 64-lane random gather over a global table is ~49
//   L1 line-transactions per instruction; tables <= LDS must be in LDS.
// R26 (keeper, -9.3us): scanpos 8-slot MLP G-loops + XCD seg decode.
// -> 171.9us champion.
// R27: hist same-bucket LDS-atomic theory: qc's float-bit bucketing has
//   ~112 hot buckets -> 64-lane atomic instr multiplicity 3-5x -> ~20us.
//   Fix: KG=1 + 2 lane-parity hist replicas (tid&1), LDS stays 32KB ->
//   4 blocks/CU preserved; within-instr same-address multiplicity halves.
//   Loads double (L2-resident, cheap per R16). hneg_g bits identical.

__device__ __forceinline__ uint32_t pack_h2(float a, float b) {
  __half2 h = __floats2half2_rn(a, b);
  return *(reinterpret_cast<uint32_t*>(&h));
}
__device__ __forceinline__ float2 unpack_h2(uint32_t u) {
  __half2 h = *(reinterpret_cast<__half2*>(&u));
  return __half22float2(h);
}

__device__ __forceinline__ float quad_qc(float ex, float ey, float ez,
                                         float sex, float sey, float sez,
                                         float tx, float ty, float tz, float A) {
  // explicit fmaf chain => bit-identical across kernels (bucket match requirement)
  float q = fmaf(ex, fmaf(sex, ex, -tx),
            fmaf(ey, fmaf(sey, ey, -ty),
            fmaf(ez, fmaf(sez, ez, -tz), A)));
  return fmaxf(q, 0.f);
}

__device__ __forceinline__ float fast_rcp(float x) { return __builtin_amdgcn_rcpf(x); }
__device__ __forceinline__ float fast_tanh(float x) {
  return 1.f - 2.f * fast_rcp(__expf(2.f * x) + 1.f);
}
__device__ __forceinline__ float fast_sigmoid(float x) {
  return fast_rcp(1.f + __expf(-x));
}

// emb compute (packed half4 out) + positive-list compaction (block reservation)
// + cooperative zeroing of hneg_g. R22: 8 points/thread (max per-wait MLP).
__global__ __launch_bounds__(256) void k_emb(
    const float* __restrict__ off, const float* __restrict__ crd,
    const float* __restrict__ seed, const int* __restrict__ inst,
    float* __restrict__ seed_bg, uint2* __restrict__ emb2,
    uint32_t* __restrict__ cursor, uint32_t* __restrict__ list,
    uint32_t* __restrict__ hneg_g)
{
  __shared__ uint32_t lcnt[K_], lbase[K_];
  __shared__ float red[4];
  const int b = blockIdx.y;
  const int tid = threadIdx.x;

  // zero hneg_g (2MB = 131072 uint4), grid-stride (492 blocks x 256 thr)
  {
    int flat = (blockIdx.y * gridDim.x + blockIdx.x) * 256 + tid;
    int stride = gridDim.x * gridDim.y * 256;
    for (int i = flat; i < (2097152 / 16); i += stride)
      ((uint4*)hneg_g)[i] = make_uint4(0u, 0u, 0u, 0u);
  }

  if (tid < K_) lcnt[tid] = 0;
  __syncthreads();

  const int n0 = blockIdx.x * 2048 + tid * 8;   // N_ % 8 == 0 (250000/8=31250)
  int kv[8];
  const bool valid = (n0 < N_);
  float sbg = 0.f;

  if (valid) {
    const int idx = b * N_ + n0;                // idx%8==0 -> 96B-aligned *3
    const float4* o4 = (const float4*)&off[(size_t)idx * 3];
    const float4* c4 = (const float4*)&crd[(size_t)idx * 3];
    float4 oA = o4[0], oB = o4[1], oC = o4[2], oD = o4[3], oE = o4[4], oF = o4[5];
    float4 cA = c4[0], cB = c4[1], cC = c4[2], cD = c4[3], cE = c4[4], cF = c4[5];
    float4 sd0 = *(const float4*)&seed[idx];
    float4 sd1 = *(const float4*)&seed[idx + 4];
    int4 ki0 = *(const int4*)&inst[idx];
    int4 ki1 = *(const int4*)&inst[idx + 4];
    kv[0] = ki0.x; kv[1] = ki0.y; kv[2] = ki0.z; kv[3] = ki0.w;
    kv[4] = ki1.x; kv[5] = ki1.y; kv[6] = ki1.z; kv[7] = ki1.w;

    // pts 0-3 from oA..oC / cA..cC (identical chain to R20's 4-pt block)
    float ex0 = fast_tanh(oA.x) + cA.x, ey0 = fast_tanh(oA.y) + cA.y, ez0 = fast_tanh(oA.z) + cA.z;
    float ex1 = fast_tanh(oA.w) + cA.w, ey1 = fast_tanh(oB.x) + cB.x, ez1 = fast_tanh(oB.y) + cB.y;
    float ex2 = fast_tanh(oB.z) + cB.z, ey2 = fast_tanh(oB.w) + cB.w, ez2 = fast_tanh(oC.x) + cC.x;
    float ex3 = fast_tanh(oC.y) + cC.y, ey3 = fast_tanh(oC.z) + cC.z, ez3 = fast_tanh(oC.w) + cC.w;
    // pts 4-7 from oD..oF / cD..cF (same pattern shifted)
    float ex4 = fast_tanh(oD.x) + cD.x, ey4 = fast_tanh(oD.y) + cD.y, ez4 = fast_tanh(oD.z) + cD.z;
    float ex5 = fast_tanh(oD.w) + cD.w, ey5 = fast_tanh(oE.x) + cE.x, ez5 = fast_tanh(oE.y) + cE.y;
    float ex6 = fast_tanh(oE.z) + cE.z, ey6 = fast_tanh(oE.w) + cE.w, ez6 = fast_tanh(oF.x) + cF.x;
    float ex7 = fast_tanh(oF.y) + cF.y, ey7 = fast_tanh(oF.z) + cF.z, ez7 = fast_tanh(oF.w) + cF.w;
    uint4 w0, w1, w2, w3;
    w0.x = pack_h2(ex0, ey0); w0.y = pack_h2(ez0, 0.f);
    w0.z = pack_h2(ex1, ey1); w0.w = pack_h2(ez1, 0.f);
    w1.x = pack_h2(ex2, ey2); w1.y = pack_h2(ez2, 0.f);
    w1.z = pack_h2(ex3, ey3); w1.w = pack_h2(ez3, 0.f);
    w2.x = pack_h2(ex4, ey4); w2.y = pack_h2(ez4, 0.f);
    w2.z = pack_h2(ex5, ey5); w2.w = pack_h2(ez5, 0.f);
    w3.x = pack_h2(ex6, ey6); w3.y = pack_h2(ez6, 0.f);
    w3.z = pack_h2(ex7, ey7); w3.w = pack_h2(ez7, 0.f);
    ((uint4*)&emb2[idx])[0] = w0;   // idx % 8 == 0 -> 64B aligned
    ((uint4*)&emb2[idx])[1] = w1;
    ((uint4*)&emb2[idx])[2] = w2;
    ((uint4*)&emb2[idx])[3] = w3;

    // branch-free bg seed accumulation (97% positive -> predicate, don't branch)
    float sv[8] = {fast_sigmoid(sd0.x), fast_sigmoid(sd0.y),
                   fast_sigmoid(sd0.z), fast_sigmoid(sd0.w),
                   fast_sigmoid(sd1.x), fast_sigmoid(sd1.y),
                   fast_sigmoid(sd1.z), fast_sigmoid(sd1.w)};
#pragma unroll
    for (int j = 0; j < 8; ++j) {
      if (kv[j] >= 0) {
        atomicAdd(&lcnt[kv[j]], 1u);
      }
      sbg = fmaf((kv[j] < 0) ? sv[j] : 0.f, sv[j], sbg);
    }
  }
  __syncthreads();
  if (tid < K_) {
    uint32_t c = lcnt[tid];
    lbase[tid] = c ? atomicAdd(&cursor[b * K_ + tid], c) : 0u;
    lcnt[tid] = 0;
  }
  __syncthreads();
  if (valid) {
#pragma unroll
    for (int j = 0; j < 8; ++j) {
      if (kv[j] >= 0) {
        uint32_t r = atomicAdd(&lcnt[kv[j]], 1u);
        list[(uint32_t)((b * K_ + kv[j]) << SLOT_SHIFT) + lbase[kv[j]] + r] =
            (uint32_t)(n0 + j);
      }
    }
  }
  for (int d = 32; d > 0; d >>= 1) sbg += __shfl_down(sbg, d, 64);
  int wid = tid >> 6, lane = tid & 63;
  if (lane == 0) red[wid] = sbg;
  __syncthreads();
  if (tid == 0) atomicAdd(&seed_bg[b], red[0] + red[1] + red[2] + red[3]);
}

// per-seg stats as a clean reduction over the compacted list (no contention)
__global__ __launch_bounds__(256) void k_segstats(
    const uint2* __restrict__ emb2, const float* __restrict__ sig,
    const uint32_t* __restrict__ list, const uint32_t* __restrict__ cursor,
    float* __restrict__ acc)
{
  __shared__ float red[4 * 8];
  const int seg = blockIdx.x >> 2;        // / SC
  const int c = blockIdx.x & (SC - 1);
  const int b = seg >> 5;
  const int G = (int)cursor[seg];
  if (G == 0) return;
  const int i0 = (int)((long)G * c / SC);
  const int i1 = (int)((long)G * (c + 1) / SC);
  const int base = b * N_;
  const uint32_t lo = (uint32_t)(seg << SLOT_SHIFT);
  const int tid = threadIdx.x;

  float sex_ = 0.f, sey_ = 0.f, sez_ = 0.f;
  float ssx = 0.f, ssy = 0.f, ssz = 0.f, ss2 = 0.f;
  for (int i = i0 + tid; i < i1; i += 256) {
    int idx = base + (int)list[lo + i];
    uint2 e = emb2[idx];
    float2 xy = unpack_h2(e.x);
    float2 zw = unpack_h2(e.y);
    float sx = sig[(size_t)idx * 3 + 0];
    float sy = sig[(size_t)idx * 3 + 1];
    float sz = sig[(size_t)idx * 3 + 2];
    sex_ += xy.x; sey_ += xy.y; sez_ += zw.x;
    ssx += sx; ssy += sy; ssz += sz;
    ss2 = fmaf(sx, sx, fmaf(sy, sy, fmaf(sz, sz, ss2)));
  }
  for (int d = 32; d > 0; d >>= 1) {
    sex_ += __shfl_down(sex_, d, 64); sey_ += __shfl_down(sey_, d, 64);
    sez_ += __shfl_down(sez_, d, 64); ssx  += __shfl_down(ssx,  d, 64);
    ssy  += __shfl_down(ssy,  d, 64); ssz  += __shfl_down(ssz,  d, 64);
    ss2  += __shfl_down(ss2,  d, 64);
  }
  int wid = tid >> 6, lane = tid & 63;
  if (lane == 0) {
    float* r = &red[wid * 8];
    r[0] = sex_; r[1] = sey_; r[2] = sez_;
    r[3] = ssx;  r[4] = ssy;  r[5] = ssz; r[6] = ss2;
  }
  __syncthreads();
  if (tid == 0) {
    float v[7];
    for (int f = 0; f < 7; ++f)
      v[f] = red[f] + red[8 + f] + red[16 + f] + red[24 + f];
    float* a = &acc[seg * 8];
    atomicAdd(&a[0], (float)(i1 - i0));
    atomicAdd(&a[1], v[0]); atomicAdd(&a[2], v[1]); atomicAdd(&a[3], v[2]);
    atomicAdd(&a[4], v[3]); atomicAdd(&a[5], v[4]); atomicAdd(&a[6], v[5]);
    atomicAdd(&a[7], v[6]);
  }
}

// histogram, R27 form: KG=1 (one seg/block, grid 2048 XCD-decoded) with
// TWO lane-parity LDS hist replicas (tid&1 -> 16KB each, 32KB total ->
// 4 blocks/CU preserved). Halves within-instruction same-bucket atomic
// serialization (the modeled ~20us). Flush sums replicas (integer-exact).
// Per-seg params computed from acc with the SAME expression chain as
// before -> p05 / bucket bits identical. c==0 block writes p05.
__global__ __launch_bounds__(512, 8) void k_hist(
    const uint2* __restrict__ emb2, const float* __restrict__ acc,
    float* __restrict__ p05, uint32_t* __restrict__ hneg_g)
{
  __shared__ uint32_t h[2 * NB];   // 32 KB: replica 0 @0, replica 1 @NB
  const int g = blockIdx.x;
  const int xcd = g & 7;
  const int b = xcd >> 1;                       // batch -> XCD pair {2b,2b+1}
  const int sub = ((g >> 3) << 1) | (xcd & 1);  // 0..511, bijective
  const int kg = sub >> 4;                      // 0..31 (seg within batch)
  const int c = sub & (HCH - 1);                // 0..15
  const int seg = b * K_ + kg;
  const int tid = threadIdx.x;

  const float* a = &acc[seg * 8];
  float counts = a[0];
  float cnt = fmaxf(counts, 1.f);
  float inv = 1.f / cnt;
  float cx = a[1] * inv, cy = a[2] * inv, cz = a[3] * inv;
  float skx = a[4] * inv, sky = a[5] * inv, skz = a[6] * inv;
  float sex = expf(10.f * skx), sey = expf(10.f * sky), sez = expf(10.f * skz);
  float tx = 2.f * sex * cx, ty = 2.f * sey * cy, tz = 2.f * sez * cz;
  float A = sex * cx * cx + sey * cy * cy + sez * cz * cz;
  if (c == 0 && tid == 0) {
    float dev2 = a[7] - 2.f * (a[4] * skx + a[5] * sky + a[6] * skz)
               + counts * (skx * skx + sky * sky + skz * skz);
    float* o = &p05[seg * 16];
    o[0] = sex; o[1] = sey; o[2] = sez;
    o[3] = tx; o[4] = ty; o[5] = tz;
    o[6] = A; o[7] = counts;
    o[8] = (counts > 0.f) ? 1.f : 0.f; o[9] = dev2 / (cnt * 3.f);
  }
  for (int i = tid; i < 2 * NB; i += 512) h[i] = 0;
  __syncthreads();

  const uint32_t roff = (tid & 1) ? NB : 0;   // lane-parity replica select
  const int base = b * N_;
  const int n0 = c * (N_ / HCH);            // 15625-point chunk
  const int nfull = n0 + 12288;             // 3 full 4096-pt stripes (8/thread)
  const int n1 = n0 + (N_ / HCH);
  for (int n = n0 + tid; n < nfull; n += 4096) {
    uint2 e0 = emb2[base + n];
    uint2 e1 = emb2[base + n + 512];
    uint2 e2 = emb2[base + n + 1024];
    uint2 e3 = emb2[base + n + 1536];
    uint2 e4 = emb2[base + n + 2048];
    uint2 e5 = emb2[base + n + 2560];
    uint2 e6 = emb2[base + n + 3072];
    uint2 e7 = emb2[base + n + 3584];
    float2 x0 = unpack_h2(e0.x), z0 = unpack_h2(e0.y);
    float2 x1 = unpack_h2(e1.x), z1 = unpack_h2(e1.y);
    float2 x2 = unpack_h2(e2.x), z2 = unpack_h2(e2.y);
    float2 x3 = unpack_h2(e3.x), z3 = unpack_h2(e3.y);
    float2 x4 = unpack_h2(e4.x), z4 = unpack_h2(e4.y);
    float2 x5 = unpack_h2(e5.x), z5 = unpack_h2(e5.y);
    float2 x6 = unpack_h2(e6.x), z6 = unpack_h2(e6.y);
    float2 x7 = unpack_h2(e7.x), z7 = unpack_h2(e7.y);
    float q0 = quad_qc(x0.x, x0.y, z0.x, sex, sey, sez, tx, ty, tz, A);
    float q1 = quad_qc(x1.x, x1.y, z1.x, sex, sey, sez, tx, ty, tz, A);
    float q2 = quad_qc(x2.x, x2.y, z2.x, sex, sey, sez, tx, ty, tz, A);
    float q3 = quad_qc(x3.x, x3.y, z3.x, sex, sey, sez, tx, ty, tz, A);
    float q4 = quad_qc(x4.x, x4.y, z4.x, sex, sey, sez, tx, ty, tz, A);
    float q5 = quad_qc(x5.x, x5.y, z5.x, sex, sey, sez, tx, ty, tz, A);
    float q6 = quad_qc(x6.x, x6.y, z6.x, sex, sey, sez, tx, ty, tz, A);
    float q7 = quad_qc(x7.x, x7.y, z7.x, sex, sey, sez, tx, ty, tz, A);
    atomicAdd(&h[roff + (__float_as_uint(q0) >> 19)], 1u);
    atomicAdd(&h[roff + (__float_as_uint(q1) >> 19)], 1u);
    atomicAdd(&h[roff + (__float_as_uint(q2) >> 19)], 1u);
    atomicAdd(&h[roff + (__float_as_uint(q3) >> 19)], 1u);
    atomicAdd(&h[roff + (__float_as_uint(q4) >> 19)], 1u);
    atomicAdd(&h[roff + (__float_as_uint(q5) >> 19)], 1u);
    atomicAdd(&h[roff + (__float_as_uint(q6) >> 19)], 1u);
    atomicAdd(&h[roff + (__float_as_uint(q7) >> 19)], 1u);
  }
  for (int n = nfull + tid; n < n1; n += 512) {   // 3337-pt tail
    uint2 e = emb2[base + n];
    float2 xy = unpack_h2(e.x);
    float2 zw = unpack_h2(e.y);
    float qc = quad_qc(xy.x, xy.y, zw.x, sex, sey, sez, tx, ty, tz, A);
    atomicAdd(&h[roff + (__float_as_uint(qc) >> 19)], 1u);
  }
  __syncthreads();
  uint32_t* gn = &hneg_g[seg * NB];
  for (int i = tid; i < NB; i += 512) {
    uint32_t v = h[i] + h[NB + i];
    if (v) atomicAdd(&gn[i], v);
  }
}

__device__ __forceinline__ void scan_excl(uint32_t* h, uint32_t* wsum, int tid)
{
  const int chunk = NB >> 10;  // 4
  const int base = tid * chunk;
  uint32_t vals[4];
  uint32_t s = 0;
  for (int i = 0; i < chunk; ++i) { vals[i] = h[base + i]; s += vals[i]; }
  uint32_t x = s;
  int lane = tid & 63;
  for (int d = 1; d < 64; d <<= 1) {
    uint32_t y = (uint32_t)__shfl_up((int)x, d, 64);
    if (lane >= d) x += y;
  }
  int wid = tid >> 6;
  if (lane == 63) wsum[wid] = x;
  __syncthreads();
  if (tid == 0) {
    uint32_t a = 0;
    for (int w = 0; w < 16; ++w) { uint32_t t = wsum[w]; wsum[w] = a; a += t; }
  }
  __syncthreads();
  uint32_t run = wsum[wid] + (x - s);
  for (int i = 0; i < chunk; ++i) { uint32_t t = vals[i]; h[base + i] = run; run += t; }
  __syncthreads();
}

// per-seg: remove positives from neg hist, build pos hist, scan both,
// emit COARSE fused neg table {u,v} (NB2), compute positive contributions
// (incl. subtracting the spurious coarse neg-style term pass2neg will add).
// R26: 8-slot MLP G-loops (G<=8192 = list capacity; slots i=tid+k*1024).
// Fixup's emb2 loads + qc persist in registers -> 2nd loop needs no
// list/emb2 gathers. Scalar tail loops preserved for G>8192 (dead).
// R26: XCD-aligned seg decode (batch -> XCD pair, matches hist/pass2neg).
__global__ __launch_bounds__(1024) void k_scanpos(
    const uint2* __restrict__ emb2, const float* __restrict__ seed,
    const float* __restrict__ p05, const uint32_t* __restrict__ list,
    uint32_t* __restrict__ hneg_g, float2* __restrict__ tabN,
    float* __restrict__ lov_out, float* __restrict__ seed_fg)
{
  __shared__ uint32_t hn[NB];
  __shared__ uint32_t hp[NB];
  __shared__ uint32_t wsum[16];
  __shared__ float red[32];
  const int g = blockIdx.x;
  const int xcd = g & 7;
  const int b = xcd >> 1;                       // batch -> XCD pair {2b,2b+1}
  const int seg = b * K_ + (((g >> 3) << 1) | (xcd & 1));  // bijective, 128
  const float* pp = &p05[seg * 16];
  const float Gf = pp[7];
  if (Gf <= 0.f) return;     // pass2neg skips this seg too -> tabN never read
  const float sex = pp[0], sey = pp[1], sez = pp[2];
  const float tx = pp[3], ty = pp[4], tz = pp[5], A = pp[6];
  const int tid = threadIdx.x;
  const int base = b * N_;
  const int G = (int)Gf;
  const uint32_t lo = (uint32_t)(seg << SLOT_SHIFT);
  const float Nnegf = (float)N_ - Gf;

  uint32_t* gn = &hneg_g[seg * NB];
  for (int i = tid; i < NB; i += 1024) { hn[i] = gn[i]; hp[i] = 0; }

  // issue all 8 slot list-loads + emb2 gathers up front (R22 MLP mechanism)
  int nn[8];
#pragma unroll
  for (int k = 0; k < 8; ++k) {
    int i = tid + (k << 10);
    nn[k] = (i < G) ? (int)list[lo + i] : -1;
  }
  uint2 ee[8];
#pragma unroll
  for (int k = 0; k < 8; ++k)
    if (nn[k] >= 0) ee[k] = emb2[base + nn[k]];
  float qcv[8];
  __syncthreads();

  // fixup: move this seg's positives out of hn, into hp
#pragma unroll
  for (int k = 0; k < 8; ++k) {
    if (nn[k] >= 0) {
      float2 xy = unpack_h2(ee[k].x);
      float2 zw = unpack_h2(ee[k].y);
      float qc = quad_qc(xy.x, xy.y, zw.x, sex, sey, sez, tx, ty, tz, A);
      qcv[k] = qc;
      atomicAdd(&hn[__float_as_uint(qc) >> 19], 0xFFFFFFFFu);  // -1
      float p = __expf(-qc);
      float qs = -__logf(1.f - p);   // p==1 -> +inf -> bucket 4080, fine
      atomicAdd(&hp[__float_as_uint(qs) >> 19], 1u);
    }
  }
  for (int i = tid + 8192; i < G; i += 1024) {   // dead in practice
    int n = (int)list[lo + i];
    uint2 e = emb2[base + n];
    float2 xy = unpack_h2(e.x);
    float2 zw = unpack_h2(e.y);
    float qc = quad_qc(xy.x, xy.y, zw.x, sex, sey, sez, tx, ty, tz, A);
    atomicAdd(&hn[__float_as_uint(qc) >> 19], 0xFFFFFFFFu);
    float p = __expf(-qc);
    float qs = -__logf(1.f - p);
    atomicAdd(&hp[__float_as_uint(qs) >> 19], 1u);
  }
  __syncthreads();
  scan_excl(hn, wsum, tid);
  scan_excl(hp, wsum, tid);

  // coarse fused neg table (sampled from fine cumulative scans at even idx)
  float2* tN = &tabN[(size_t)seg * NB2];
  for (int bkt = tid; bkt < NB2; bkt += 1024) {
    float R  = (float)hn[2 * bkt];
    float nn2_ = (bkt < NB2 - 1) ? (float)hn[2 * bkt + 2] : Nnegf;
    float m  = nn2_ - R;
    float pb = (float)hp[2 * bkt];
    float pn = (bkt < NB2 - 1) ? (float)hp[2 * bkt + 2] : Gf;
    float gr = Gf + R;
    float psi2 = 2.f / (gr * (gr + m));
    float u = psi2 * (Gf - pb);
    float v = psi2 * (pn - pb) * (1.f / 1048576.f);
    tN[bkt] = make_float2(u, v);
  }

  // positives' own contributions — issue all 8 seed gathers up front;
  // emb2/qc reused from registers (no list/emb2 re-gather).
  float sdv[8];
#pragma unroll
  for (int k = 0; k < 8; ++k)
    if (nn[k] >= 0) sdv[k] = seed[base + nn[k]];

  float lov = 0.f, sfg = 0.f;
#pragma unroll
  for (int k = 0; k < 8; ++k) {
    if (nn[k] >= 0) {
      float qc = qcv[k];
      float p = __expf(-qc);
      float qs = -__logf(1.f - p);
      uint32_t qb = __float_as_uint(qs);
      uint32_t bk = qb >> 19;
      float frac = (float)(qb & 0x7FFFFu) * (1.f / 524288.f);
      float R  = (float)hn[bk];
      float nnv = (bk < NB - 1) ? (float)hn[bk + 1] : Nnegf;
      float F = R + frac * (nnv - R);
      lov += (2.f - 2.f * p) / (Gf + F);
      float s = fast_sigmoid(sdv[k]);
      float d = s - p;
      sfg += d * d;
      // subtract the spurious COARSE neg-style term (bit-identical to table path)
      uint32_t cb = __float_as_uint(qc);
      uint32_t b2 = cb >> 20;
      float fr = (float)(cb & 0xFFFFFu);
      float R2  = (float)hn[2 * b2];
      float nn2_ = (b2 < NB2 - 1) ? (float)hn[2 * b2 + 2] : Nnegf;
      float m2  = nn2_ - R2;
      float pb2 = (float)hp[2 * b2];
      float pn2 = (b2 < NB2 - 1) ? (float)hp[2 * b2 + 2] : Gf;
      float gr2 = Gf + R2;
      float psi2 = 2.f / (gr2 * (gr2 + m2));
      float u2 = psi2 * (Gf - pb2);
      float v2 = psi2 * (pn2 - pb2) * (1.f / 1048576.f);
      lov -= p * fmaf(-v2, fr, u2);
    }
  }
  for (int i = tid + 8192; i < G; i += 1024) {   // dead in practice
    int n = (int)list[lo + i];
    uint2 e = emb2[base + n];
    float2 xy = unpack_h2(e.x);
    float2 zw = unpack_h2(e.y);
    float qc = quad_qc(xy.x, xy.y, zw.x, sex, sey, sez, tx, ty, tz, A);
    float p = __expf(-qc);
    float qs = -__logf(1.f - p);
    uint32_t qb = __float_as_uint(qs);
    uint32_t bk = qb >> 19;
    float frac = (float)(qb & 0x7FFFFu) * (1.f / 524288.f);
    float R  = (float)hn[bk];
    float nnv = (bk < NB - 1) ? (float)hn[bk + 1] : Nnegf;
    float F = R + frac * (nnv - R);
    lov += (2.f - 2.f * p) / (Gf + F);
    float s = fast_sigmoid(seed[base + n]);
    float d = s - p;
    sfg += d * d;
    uint32_t cb = __float_as_uint(qc);
    uint32_t b2 = cb >> 20;
    float fr = (float)(cb & 0xFFFFFu);
    float R2  = (float)hn[2 * b2];
    float nn2_ = (b2 < NB2 - 1) ? (float)hn[2 * b2 + 2] : Nnegf;
    float m2  = nn2_ - R2;
    float pb2 = (float)hp[2 * b2];
    float pn2 = (b2 < NB2 - 1) ? (float)hp[2 * b2 + 2] : Gf;
    float gr2 = Gf + R2;
    float psi2 = 2.f / (gr2 * (gr2 + m2));
    float u2 = psi2 * (Gf - pb2);
    float v2 = psi2 * (pn2 - pb2) * (1.f / 1048576.f);
    lov -= p * fmaf(-v2, fr, u2);
  }

  for (int d = 32; d > 0; d >>= 1) {
    lov += __shfl_down(lov, d, 64);
    sfg += __shfl_down(sfg, d, 64);
  }
  int wid = tid >> 6, lane = tid & 63;
  if (lane == 0) { red[wid] = lov; red[16 + wid] = sfg; }
  __syncthreads();
  if (tid == 0) {
    float lt = 0.f, st = 0.f;
    for (int w = 0; w < 16; ++w) { lt += red[w]; st += red[16 + w]; }
    atomicAdd(&lov_out[seg], lt);
    atomicAdd(&seed_fg[b], st);
  }
}

// branch-free negative pass — 8B packed emb, 1 seg/block, 256 thr.
// R25: tabN staged in LDS (16KB) — the global gather was ~49 L1 lines/inst.
// Do NOT regroup (R10/R11). NO device-scope fence/atomic epilogue (R14).
// R17: XCD-clustered decode (batch -> XCD pair) for L2-resident emb2.
// R23: 8-pt stripes; launch_bounds(256,8) pins 8 blocks/CU.
__global__ __launch_bounds__(256, 8) void k_pass2neg(
    const uint2* __restrict__ emb2, const float* __restrict__ p05,
    const float2* __restrict__ tabN, float* __restrict__ lov_out)
{
  __shared__ float red[4];
  __shared__ float2 stab[NB2];   // 16 KB
  const int g = blockIdx.x;
  const int xcd = g & 7;
  const int bb = xcd >> 1;                      // batch -> XCD pair {2b,2b+1}
  const int sub = ((g >> 3) << 1) | (xcd & 1);  // 0..511, bijective
  const int seg = bb * K_ + (sub >> 4);
  const int chunk = sub & (S2 - 1);
  const int b = bb;
  const float* pp = &p05[seg * 16];
  const float Gf = pp[7];
  if (Gf <= 0.f) return;                        // block-uniform -> barrier-safe
  const float sex = pp[0], sey = pp[1], sez = pp[2];
  const float tx = pp[3], ty = pp[4], tz = pp[5], A = pp[6];
  const int tid = threadIdx.x;
  const int base = b * N_;
  const int n0 = chunk * (N_ / S2);         // 15625 per chunk
  const int nfull = n0 + 14336;             // 7 full 2048-pt stripes (8/thread)
  const int n1 = n0 + (N_ / S2);
  const float2* tN = &tabN[(size_t)seg * NB2];

  // stage the coarse table (2048 x 8B, coalesced) into LDS
  for (int i = tid; i < NB2; i += 256) stab[i] = tN[i];
  __syncthreads();

  float l0 = 0.f, l1 = 0.f, l2 = 0.f, l3 = 0.f;
  float l4 = 0.f, l5 = 0.f, l6 = 0.f, l7 = 0.f;
  for (int s = n0 + tid; s < nfull; s += 2048) {
    uint2 e0 = emb2[base + s];
    uint2 e1 = emb2[base + s + 256];
    uint2 e2 = emb2[base + s + 512];
    uint2 e3 = emb2[base + s + 768];
    uint2 e4 = emb2[base + s + 1024];
    uint2 e5 = emb2[base + s + 1280];
    uint2 e6 = emb2[base + s + 1536];
    uint2 e7 = emb2[base + s + 1792];
    float2 a0 = unpack_h2(e0.x), b0 = unpack_h2(e0.y);
    float2 a1 = unpack_h2(e1.x), b1 = unpack_h2(e1.y);
    float2 a2 = unpack_h2(e2.x), b2 = unpack_h2(e2.y);
    float2 a3 = unpack_h2(e3.x), b3 = unpack_h2(e3.y);
    float2 a4 = unpack_h2(e4.x), b4 = unpack_h2(e4.y);
    float2 a5 = unpack_h2(e5.x), b5 = unpack_h2(e5.y);
    float2 a6 = unpack_h2(e6.x), b6 = unpack_h2(e6.y);
    float2 a7 = unpack_h2(e7.x), b7 = unpack_h2(e7.y);
    float q0 = quad_qc(a0.x, a0.y, b0.x, sex, sey, sez, tx, ty, tz, A);
    float q1 = quad_qc(a1.x, a1.y, b1.x, sex, sey, sez, tx, ty, tz, A);
    float q2 = quad_qc(a2.x, a2.y, b2.x, sex, sey, sez, tx, ty, tz, A);
    float q3 = quad_qc(a3.x, a3.y, b3.x, sex, sey, sez, tx, ty, tz, A);
    float q4 = quad_qc(a4.x, a4.y, b4.x, sex, sey, sez, tx, ty, tz, A);
    float q5 = quad_qc(a5.x, a5.y, b5.x, sex, sey, sez, tx, ty, tz, A);
    float q6 = quad_qc(a6.x, a6.y, b6.x, sex, sey, sez, tx, ty, tz, A);
    float q7 = quad_qc(a7.x, a7.y, b7.x, sex, sey, sez, tx, ty, tz, A);
    uint32_t c0 = __float_as_uint(q0), c1 = __float_as_uint(q1);
    uint32_t c2 = __float_as_uint(q2), c3 = __float_as_uint(q3);
    uint32_t c4 = __float_as_uint(q4), c5 = __float_as_uint(q5);
    uint32_t c6 = __float_as_uint(q6), c7 = __float_as_uint(q7);
    float2 t0 = stab[c0 >> 20];
    float2 t1 = stab[c1 >> 20];
    float2 t2 = stab[c2 >> 20];
    float2 t3 = stab[c3 >> 20];
    float2 t4 = stab[c4 >> 20];
    float2 t5 = stab[c5 >> 20];
    float2 t6 = stab[c6 >> 20];
    float2 t7 = stab[c7 >> 20];
    float p0 = __expf(-q0), p1 = __expf(-q1);
    float p2 = __expf(-q2), p3 = __expf(-q3);
    float p4 = __expf(-q4), p5 = __expf(-q5);
    float p6 = __expf(-q6), p7 = __expf(-q7);
    l0 = fmaf(p0, fmaf(-t0.y, (float)(c0 & 0xFFFFFu), t0.x), l0);
    l1 = fmaf(p1, fmaf(-t1.y, (float)(c1 & 0xFFFFFu), t1.x), l1);
    l2 = fmaf(p2, fmaf(-t2.y, (float)(c2 & 0xFFFFFu), t2.x), l2);
    l3 = fmaf(p3, fmaf(-t3.y, (float)(c3 & 0xFFFFFu), t3.x), l3);
    l4 = fmaf(p4, fmaf(-t4.y, (float)(c4 & 0xFFFFFu), t4.x), l4);
    l5 = fmaf(p5, fmaf(-t5.y, (float)(c5 & 0xFFFFFu), t5.x), l5);
    l6 = fmaf(p6, fmaf(-t6.y, (float)(c6 & 0xFFFFFu), t6.x), l6);
    l7 = fmaf(p7, fmaf(-t7.y, (float)(c7 & 0xFFFFFu), t7.x), l7);
  }
  for (int n = nfull + tid; n < n1; n += 256) {   // 1289-pt tail
    uint2 e = emb2[base + n];
    float2 xy = unpack_h2(e.x);
    float2 zw = unpack_h2(e.y);
    float qc = quad_qc(xy.x, xy.y, zw.x, sex, sey, sez, tx, ty, tz, A);
    float p = __expf(-qc);
    uint32_t cb = __float_as_uint(qc);
    float2 t = stab[cb >> 20];
    l0 = fmaf(p, fmaf(-t.y, (float)(cb & 0xFFFFFu), t.x), l0);
  }

  float lov = ((l0 + l1) + (l2 + l3)) + ((l4 + l5) + (l6 + l7));
  for (int d = 32; d > 0; d >>= 1) lov += __shfl_down(lov, d, 64);
  int wid = tid >> 6, lane = tid & 63;
  if (lane == 0) red[wid] = lov;
  __syncthreads();
  if (tid == 0) {
    float lt = red[0] + red[1] + red[2] + red[3];
    atomicAdd(&lov_out[seg], lt);
  }
}

__global__ void k_final(const float* __restrict__ p05, const float* __restrict__ lov,
                        const float* __restrict__ seed_bg, const float* __restrict__ seed_fg,
                        float* __restrict__ out)
{
  __shared__ float sv[B_], sl[B_], ss[B_];
  int tid = threadIdx.x;   // 128 threads, one per seg
  if (tid < B_) { sv[tid] = 0.f; sl[tid] = 0.f; ss[tid] = 0.f; }
  __syncthreads();
  int b = tid >> 5;
  float vf = p05[tid * 16 + 8];
  atomicAdd(&sv[b], vf);
  atomicAdd(&sl[b], lov[tid] * vf);
  atomicAdd(&ss[b], p05[tid * 16 + 9] * vf);
  __syncthreads();
  if (tid == 0) {
    float total = 0.f;
    for (int bb = 0; bb < B_; ++bb) {
      float obj = fmaxf(sv[bb], 1.f);
      float seed_l = (seed_bg[bb] + seed_fg[bb]) / (float)N_;
      total += sl[bb] / obj + 10.f * (ss[bb] / obj) + 10.f * seed_l;
    }
    out[0] = total / (float)B_;
  }
}

extern "C" void kernel_launch(void* const* d_in, const int* in_sizes, int n_in,
                              void* d_out, int out_size, void* d_ws, size_t ws_size,
                              hipStream_t stream) {
  const float* off  = (const float*)d_in[0];
  const float* crd  = (const float*)d_in[1];
  const float* sig  = (const float*)d_in[2];
  const float* seed = (const float*)d_in[3];
  const int*   inst = (const int*)d_in[4];

  float* ws      = (float*)d_ws;
  float* acc     = ws;                 // 1024 floats
  float* seed_bg = ws + 1024;          // 4
  float* seed_fg = ws + 1028;          // 4
  float* lov     = ws + 1032;          // 128
  uint32_t* cursor = (uint32_t*)(ws + 1160);  // 128
  float* p05     = ws + 2048;          // byte 8192
  char* pbase = (char*)d_ws;
  uint2*    emb2   = (uint2*)(pbase + 65536);                       // 8 MB half4
  uint32_t* hneg_g = (uint32_t*)(pbase + 65536 + 8388608);          // 2 MB
  float2*   tabN   = (float2*)(pbase + 65536 + 8388608 + 2097152);  // 2 MB coarse
  uint32_t* list   = (uint32_t*)((char*)tabN + 2097152);            // 4 MB

  hipMemsetAsync(d_ws, 0, 8192, stream);   // acc/seed/lov/cursor

  dim3 ge((N_ + 2047) / 2048, B_);   // 123 x 4 — 8 pts/thread (R22: max MLP)
  k_emb<<<ge, 256, 0, stream>>>(off, crd, seed, inst, seed_bg, emb2, cursor, list,
                                hneg_g);
  k_segstats<<<B_ * K_ * SC, 256, 0, stream>>>(emb2, sig, list, cursor, acc);
  k_hist<<<B_ * K_ * HCH, 512, 0, stream>>>(emb2, acc, p05, hneg_g);  // 2048, XCD-decoded, KG=1
  k_scanpos<<<B_ * K_, 1024, 0, stream>>>(emb2, seed, p05, list, hneg_g, tabN, lov, seed_fg);  // 128, XCD-decoded
  k_pass2neg<<<B_ * K_ * S2, 256, 0, stream>>>(emb2, p05, tabN, lov);  // 2048, XCD-decoded
  k_final<<<1, 128, 0, stream>>>(p05, lov, seed_bg, seed_fg, (float*)d_out);
}

// Round 15
// 171.841 us; speedup vs baseline: 1.0099x; 1.0099x over previous
//
#include <hip/hip_runtime.h>
#include <hip/hip_fp16.h>
#include <math.h>

#define B_ 4
#define N_ 250000
#define K_ 32
#define NB 4096    // fine buckets: (bits(qc) >> 19); nonneg floats -> <= 4080
#define NB2 2048   // coarse neg-table buckets: (bits >> 20)
#define KG 2       // segs grouped per hist block (R16 KG=4-packed worse;
                   // R27 KG=1+replicas neutral-worse -> KG=2 confirmed optimum)
#define HCH 16     // hist chunks over N  (N_/16 = 15625 exact)
#define S2 16      // pass2 chunks over N (R8 shape: best measured)
#define SC 4       // segstats chunks per seg
#define SLOT_SHIFT 13  // 8192 entries per seg in list

// ws layout: small accums @0 (8KB), p05 @8192, emb2 @65536 (8MB half4),
// hneg_g @65536+8MB (2MB, zeroed inside k_emb), tabN next (2MB, NOT zeroed:
// scanpos/pass2neg both skip Gf<=0 segs), list next (4MB)
//
// Ledger of hard-won facts (R14-R27):
// - NO device-scope fences/atomics in hot kernels (L1/L2 poisoning, R14).
// - XCD-clustered block decode (batch -> XCD pair -> 2MB emb2 L2-resident)
//   on hist/scanpos/pass2neg: keeper (R17/R26).
// - MLP MECHANISM (R19/R22/R23/R24): latency-bound kernels gain from
//   PER-WAVE MLP (outstanding loads per vmcnt wait), not occupancy; gain
//   scales with uncovered latency. emb 8pt: -6.5us; pass2neg 8pt: -1.5;
//   hist 8pt (TLP-max): 0.
// - GATHER MECHANISM (R25, -13.7us): 64-lane random gather over a global
//   table is ~49 L1 line-transactions/instruction; tables <= LDS -> LDS.
// - scanpos 8-slot MLP + reg-carried qc (R26, -9.3us).
// - REFUTED: segstats fusion (R18), hist packed counters (R16), hist flush
//   de-atomization (R21), hist lane-parity replicas (R27 neutral). hist sits
//   at its DS-issue floor; emb at its L3-latency floor post-MLP.
// Champion: 171.9us (R26 config, restored here).

__device__ __forceinline__ uint32_t pack_h2(float a, float b) {
  __half2 h = __floats2half2_rn(a, b);
  return *(reinterpret_cast<uint32_t*>(&h));
}
__device__ __forceinline__ float2 unpack_h2(uint32_t u) {
  __half2 h = *(reinterpret_cast<__half2*>(&u));
  return __half22float2(h);
}

__device__ __forceinline__ float quad_qc(float ex, float ey, float ez,
                                         float sex, float sey, float sez,
                                         float tx, float ty, float tz, float A) {
  // explicit fmaf chain => bit-identical across kernels (bucket match requirement)
  float q = fmaf(ex, fmaf(sex, ex, -tx),
            fmaf(ey, fmaf(sey, ey, -ty),
            fmaf(ez, fmaf(sez, ez, -tz), A)));
  return fmaxf(q, 0.f);
}

__device__ __forceinline__ float fast_rcp(float x) { return __builtin_amdgcn_rcpf(x); }
__device__ __forceinline__ float fast_tanh(float x) {
  return 1.f - 2.f * fast_rcp(__expf(2.f * x) + 1.f);
}
__device__ __forceinline__ float fast_sigmoid(float x) {
  return fast_rcp(1.f + __expf(-x));
}

// emb compute (packed half4 out) + positive-list compaction (block reservation)
// + cooperative zeroing of hneg_g. R22: 8 points/thread (max per-wait MLP).
__global__ __launch_bounds__(256) void k_emb(
    const float* __restrict__ off, const float* __restrict__ crd,
    const float* __restrict__ seed, const int* __restrict__ inst,
    float* __restrict__ seed_bg, uint2* __restrict__ emb2,
    uint32_t* __restrict__ cursor, uint32_t* __restrict__ list,
    uint32_t* __restrict__ hneg_g)
{
  __shared__ uint32_t lcnt[K_], lbase[K_];
  __shared__ float red[4];
  const int b = blockIdx.y;
  const int tid = threadIdx.x;

  // zero hneg_g (2MB = 131072 uint4), grid-stride (492 blocks x 256 thr)
  {
    int flat = (blockIdx.y * gridDim.x + blockIdx.x) * 256 + tid;
    int stride = gridDim.x * gridDim.y * 256;
    for (int i = flat; i < (2097152 / 16); i += stride)
      ((uint4*)hneg_g)[i] = make_uint4(0u, 0u, 0u, 0u);
  }

  if (tid < K_) lcnt[tid] = 0;
  __syncthreads();

  const int n0 = blockIdx.x * 2048 + tid * 8;   // N_ % 8 == 0 (250000/8=31250)
  int kv[8];
  const bool valid = (n0 < N_);
  float sbg = 0.f;

  if (valid) {
    const int idx = b * N_ + n0;                // idx%8==0 -> 96B-aligned *3
    const float4* o4 = (const float4*)&off[(size_t)idx * 3];
    const float4* c4 = (const float4*)&crd[(size_t)idx * 3];
    float4 oA = o4[0], oB = o4[1], oC = o4[2], oD = o4[3], oE = o4[4], oF = o4[5];
    float4 cA = c4[0], cB = c4[1], cC = c4[2], cD = c4[3], cE = c4[4], cF = c4[5];
    float4 sd0 = *(const float4*)&seed[idx];
    float4 sd1 = *(const float4*)&seed[idx + 4];
    int4 ki0 = *(const int4*)&inst[idx];
    int4 ki1 = *(const int4*)&inst[idx + 4];
    kv[0] = ki0.x; kv[1] = ki0.y; kv[2] = ki0.z; kv[3] = ki0.w;
    kv[4] = ki1.x; kv[5] = ki1.y; kv[6] = ki1.z; kv[7] = ki1.w;

    // pts 0-3 from oA..oC / cA..cC (identical chain to R20's 4-pt block)
    float ex0 = fast_tanh(oA.x) + cA.x, ey0 = fast_tanh(oA.y) + cA.y, ez0 = fast_tanh(oA.z) + cA.z;
    float ex1 = fast_tanh(oA.w) + cA.w, ey1 = fast_tanh(oB.x) + cB.x, ez1 = fast_tanh(oB.y) + cB.y;
    float ex2 = fast_tanh(oB.z) + cB.z, ey2 = fast_tanh(oB.w) + cB.w, ez2 = fast_tanh(oC.x) + cC.x;
    float ex3 = fast_tanh(oC.y) + cC.y, ey3 = fast_tanh(oC.z) + cC.z, ez3 = fast_tanh(oC.w) + cC.w;
    // pts 4-7 from oD..oF / cD..cF (same pattern shifted)
    float ex4 = fast_tanh(oD.x) + cD.x, ey4 = fast_tanh(oD.y) + cD.y, ez4 = fast_tanh(oD.z) + cD.z;
    float ex5 = fast_tanh(oD.w) + cD.w, ey5 = fast_tanh(oE.x) + cE.x, ez5 = fast_tanh(oE.y) + cE.y;
    float ex6 = fast_tanh(oE.z) + cE.z, ey6 = fast_tanh(oE.w) + cE.w, ez6 = fast_tanh(oF.x) + cF.x;
    float ex7 = fast_tanh(oF.y) + cF.y, ey7 = fast_tanh(oF.z) + cF.z, ez7 = fast_tanh(oF.w) + cF.w;
    uint4 w0, w1, w2, w3;
    w0.x = pack_h2(ex0, ey0); w0.y = pack_h2(ez0, 0.f);
    w0.z = pack_h2(ex1, ey1); w0.w = pack_h2(ez1, 0.f);
    w1.x = pack_h2(ex2, ey2); w1.y = pack_h2(ez2, 0.f);
    w1.z = pack_h2(ex3, ey3); w1.w = pack_h2(ez3, 0.f);
    w2.x = pack_h2(ex4, ey4); w2.y = pack_h2(ez4, 0.f);
    w2.z = pack_h2(ex5, ey5); w2.w = pack_h2(ez5, 0.f);
    w3.x = pack_h2(ex6, ey6); w3.y = pack_h2(ez6, 0.f);
    w3.z = pack_h2(ex7, ey7); w3.w = pack_h2(ez7, 0.f);
    ((uint4*)&emb2[idx])[0] = w0;   // idx % 8 == 0 -> 64B aligned
    ((uint4*)&emb2[idx])[1] = w1;
    ((uint4*)&emb2[idx])[2] = w2;
    ((uint4*)&emb2[idx])[3] = w3;

    // branch-free bg seed accumulation (97% positive -> predicate, don't branch)
    float sv[8] = {fast_sigmoid(sd0.x), fast_sigmoid(sd0.y),
                   fast_sigmoid(sd0.z), fast_sigmoid(sd0.w),
                   fast_sigmoid(sd1.x), fast_sigmoid(sd1.y),
                   fast_sigmoid(sd1.z), fast_sigmoid(sd1.w)};
#pragma unroll
    for (int j = 0; j < 8; ++j) {
      if (kv[j] >= 0) {
        atomicAdd(&lcnt[kv[j]], 1u);
      }
      sbg = fmaf((kv[j] < 0) ? sv[j] : 0.f, sv[j], sbg);
    }
  }
  __syncthreads();
  if (tid < K_) {
    uint32_t c = lcnt[tid];
    lbase[tid] = c ? atomicAdd(&cursor[b * K_ + tid], c) : 0u;
    lcnt[tid] = 0;
  }
  __syncthreads();
  if (valid) {
#pragma unroll
    for (int j = 0; j < 8; ++j) {
      if (kv[j] >= 0) {
        uint32_t r = atomicAdd(&lcnt[kv[j]], 1u);
        list[(uint32_t)((b * K_ + kv[j]) << SLOT_SHIFT) + lbase[kv[j]] + r] =
            (uint32_t)(n0 + j);
      }
    }
  }
  for (int d = 32; d > 0; d >>= 1) sbg += __shfl_down(sbg, d, 64);
  int wid = tid >> 6, lane = tid & 63;
  if (lane == 0) red[wid] = sbg;
  __syncthreads();
  if (tid == 0) atomicAdd(&seed_bg[b], red[0] + red[1] + red[2] + red[3]);
}

// per-seg stats as a clean reduction over the compacted list (no contention)
__global__ __launch_bounds__(256) void k_segstats(
    const uint2* __restrict__ emb2, const float* __restrict__ sig,
    const uint32_t* __restrict__ list, const uint32_t* __restrict__ cursor,
    float* __restrict__ acc)
{
  __shared__ float red[4 * 8];
  const int seg = blockIdx.x >> 2;        // / SC
  const int c = blockIdx.x & (SC - 1);
  const int b = seg >> 5;
  const int G = (int)cursor[seg];
  if (G == 0) return;
  const int i0 = (int)((long)G * c / SC);
  const int i1 = (int)((long)G * (c + 1) / SC);
  const int base = b * N_;
  const uint32_t lo = (uint32_t)(seg << SLOT_SHIFT);
  const int tid = threadIdx.x;

  float sex_ = 0.f, sey_ = 0.f, sez_ = 0.f;
  float ssx = 0.f, ssy = 0.f, ssz = 0.f, ss2 = 0.f;
  for (int i = i0 + tid; i < i1; i += 256) {
    int idx = base + (int)list[lo + i];
    uint2 e = emb2[idx];
    float2 xy = unpack_h2(e.x);
    float2 zw = unpack_h2(e.y);
    float sx = sig[(size_t)idx * 3 + 0];
    float sy = sig[(size_t)idx * 3 + 1];
    float sz = sig[(size_t)idx * 3 + 2];
    sex_ += xy.x; sey_ += xy.y; sez_ += zw.x;
    ssx += sx; ssy += sy; ssz += sz;
    ss2 = fmaf(sx, sx, fmaf(sy, sy, fmaf(sz, sz, ss2)));
  }
  for (int d = 32; d > 0; d >>= 1) {
    sex_ += __shfl_down(sex_, d, 64); sey_ += __shfl_down(sey_, d, 64);
    sez_ += __shfl_down(sez_, d, 64); ssx  += __shfl_down(ssx,  d, 64);
    ssy  += __shfl_down(ssy,  d, 64); ssz  += __shfl_down(ssz,  d, 64);
    ss2  += __shfl_down(ss2,  d, 64);
  }
  int wid = tid >> 6, lane = tid & 63;
  if (lane == 0) {
    float* r = &red[wid * 8];
    r[0] = sex_; r[1] = sey_; r[2] = sez_;
    r[3] = ssx;  r[4] = ssy;  r[5] = ssz; r[6] = ss2;
  }
  __syncthreads();
  if (tid == 0) {
    float v[7];
    for (int f = 0; f < 7; ++f)
      v[f] = red[f] + red[8 + f] + red[16 + f] + red[24 + f];
    float* a = &acc[seg * 8];
    atomicAdd(&a[0], (float)(i1 - i0));
    atomicAdd(&a[1], v[0]); atomicAdd(&a[2], v[1]); atomicAdd(&a[3], v[2]);
    atomicAdd(&a[4], v[3]); atomicAdd(&a[5], v[4]); atomicAdd(&a[6], v[5]);
    atomicAdd(&a[7], v[6]);
  }
}

// grouped histogram: KG=2 segs share each emb load; 2 x 16KB LDS hists
// -> 32KB/block -> 4 blocks/CU -> 32 waves/CU (100% occupancy cap).
// Per-seg params computed here from acc; chunk-0 block writes p05 (bucket-match).
// R17: XCD-clustered decode (batch -> XCD pair) for L2-resident emb2.
// R24: 8-pt stripe eval. R27's KG=1+replicas was neutral-worse — reverted.
__global__ __launch_bounds__(512, 8) void k_hist(
    const uint2* __restrict__ emb2, const float* __restrict__ acc,
    float* __restrict__ p05, uint32_t* __restrict__ hneg_g)
{
  __shared__ uint32_t h[KG * NB];   // 32 KB
  const int g = blockIdx.x;
  const int xcd = g & 7;
  const int b = xcd >> 1;                       // batch -> XCD pair {2b,2b+1}
  const int sub = ((g >> 3) << 1) | (xcd & 1);  // 0..255, bijective
  const int kg = sub >> 4;                      // 0..15
  const int c = sub & (HCH - 1);                // 0..15
  const int seg0 = b * K_ + kg * KG;
  const int tid = threadIdx.x;

  float sexA[KG], seyA[KG], sezA[KG], txA[KG], tyA[KG], tzA[KG], AA[KG];
#pragma unroll
  for (int j = 0; j < KG; ++j) {
    const float* a = &acc[(seg0 + j) * 8];
    float counts = a[0];
    float cnt = fmaxf(counts, 1.f);
    float inv = 1.f / cnt;
    float cx = a[1] * inv, cy = a[2] * inv, cz = a[3] * inv;
    float skx = a[4] * inv, sky = a[5] * inv, skz = a[6] * inv;
    sexA[j] = expf(10.f * skx); seyA[j] = expf(10.f * sky); sezA[j] = expf(10.f * skz);
    txA[j] = 2.f * sexA[j] * cx; tyA[j] = 2.f * seyA[j] * cy; tzA[j] = 2.f * sezA[j] * cz;
    AA[j] = sexA[j] * cx * cx + seyA[j] * cy * cy + sezA[j] * cz * cz;
    if (c == 0 && tid == 0) {
      float dev2 = a[7] - 2.f * (a[4] * skx + a[5] * sky + a[6] * skz)
                 + counts * (skx * skx + sky * sky + skz * skz);
      float* o = &p05[(seg0 + j) * 16];
      o[0] = sexA[j]; o[1] = seyA[j]; o[2] = sezA[j];
      o[3] = txA[j]; o[4] = tyA[j]; o[5] = tzA[j];
      o[6] = AA[j]; o[7] = counts;
      o[8] = (counts > 0.f) ? 1.f : 0.f; o[9] = dev2 / (cnt * 3.f);
    }
  }
  for (int i = tid; i < KG * NB; i += 512) h[i] = 0;
  __syncthreads();

  const int base = b * N_;
  const int n0 = c * (N_ / HCH);            // 15625-point chunk
  const int nfull = n0 + 12288;             // 3 full 4096-pt stripes (8/thread)
  const int n1 = n0 + (N_ / HCH);
  for (int n = n0 + tid; n < nfull; n += 4096) {
    uint2 e0 = emb2[base + n];
    uint2 e1 = emb2[base + n + 512];
    uint2 e2 = emb2[base + n + 1024];
    uint2 e3 = emb2[base + n + 1536];
    uint2 e4 = emb2[base + n + 2048];
    uint2 e5 = emb2[base + n + 2560];
    uint2 e6 = emb2[base + n + 3072];
    uint2 e7 = emb2[base + n + 3584];
    float2 x0 = unpack_h2(e0.x), z0 = unpack_h2(e0.y);
    float2 x1 = unpack_h2(e1.x), z1 = unpack_h2(e1.y);
    float2 x2 = unpack_h2(e2.x), z2 = unpack_h2(e2.y);
    float2 x3 = unpack_h2(e3.x), z3 = unpack_h2(e3.y);
    float2 x4 = unpack_h2(e4.x), z4 = unpack_h2(e4.y);
    float2 x5 = unpack_h2(e5.x), z5 = unpack_h2(e5.y);
    float2 x6 = unpack_h2(e6.x), z6 = unpack_h2(e6.y);
    float2 x7 = unpack_h2(e7.x), z7 = unpack_h2(e7.y);
#pragma unroll
    for (int j = 0; j < KG; ++j) {
      float q0 = quad_qc(x0.x, x0.y, z0.x, sexA[j], seyA[j], sezA[j], txA[j], tyA[j], tzA[j], AA[j]);
      float q1 = quad_qc(x1.x, x1.y, z1.x, sexA[j], seyA[j], sezA[j], txA[j], tyA[j], tzA[j], AA[j]);
      float q2 = quad_qc(x2.x, x2.y, z2.x, sexA[j], seyA[j], sezA[j], txA[j], tyA[j], tzA[j], AA[j]);
      float q3 = quad_qc(x3.x, x3.y, z3.x, sexA[j], seyA[j], sezA[j], txA[j], tyA[j], tzA[j], AA[j]);
      float q4 = quad_qc(x4.x, x4.y, z4.x, sexA[j], seyA[j], sezA[j], txA[j], tyA[j], tzA[j], AA[j]);
      float q5 = quad_qc(x5.x, x5.y, z5.x, sexA[j], seyA[j], sezA[j], txA[j], tyA[j], tzA[j], AA[j]);
      float q6 = quad_qc(x6.x, x6.y, z6.x, sexA[j], seyA[j], sezA[j], txA[j], tyA[j], tzA[j], AA[j]);
      float q7 = quad_qc(x7.x, x7.y, z7.x, sexA[j], seyA[j], sezA[j], txA[j], tyA[j], tzA[j], AA[j]);
      atomicAdd(&h[j * NB + (__float_as_uint(q0) >> 19)], 1u);
      atomicAdd(&h[j * NB + (__float_as_uint(q1) >> 19)], 1u);
      atomicAdd(&h[j * NB + (__float_as_uint(q2) >> 19)], 1u);
      atomicAdd(&h[j * NB + (__float_as_uint(q3) >> 19)], 1u);
      atomicAdd(&h[j * NB + (__float_as_uint(q4) >> 19)], 1u);
      atomicAdd(&h[j * NB + (__float_as_uint(q5) >> 19)], 1u);
      atomicAdd(&h[j * NB + (__float_as_uint(q6) >> 19)], 1u);
      atomicAdd(&h[j * NB + (__float_as_uint(q7) >> 19)], 1u);
    }
  }
  for (int n = nfull + tid; n < n1; n += 512) {   // 3337-pt tail
    uint2 e = emb2[base + n];
    float2 xy = unpack_h2(e.x);
    float2 zw = unpack_h2(e.y);
#pragma unroll
    for (int j = 0; j < KG; ++j) {
      float qc = quad_qc(xy.x, xy.y, zw.x,
                         sexA[j], seyA[j], sezA[j], txA[j], tyA[j], tzA[j], AA[j]);
      atomicAdd(&h[j * NB + (__float_as_uint(qc) >> 19)], 1u);
    }
  }
  __syncthreads();
#pragma unroll
  for (int j = 0; j < KG; ++j) {
    uint32_t* gn = &hneg_g[(seg0 + j) * NB];
    for (int i = tid; i < NB; i += 512) {
      uint32_t v = h[j * NB + i];
      if (v) atomicAdd(&gn[i], v);
    }
  }
}

__device__ __forceinline__ void scan_excl(uint32_t* h, uint32_t* wsum, int tid)
{
  const int chunk = NB >> 10;  // 4
  const int base = tid * chunk;
  uint32_t vals[4];
  uint32_t s = 0;
  for (int i = 0; i < chunk; ++i) { vals[i] = h[base + i]; s += vals[i]; }
  uint32_t x = s;
  int lane = tid & 63;
  for (int d = 1; d < 64; d <<= 1) {
    uint32_t y = (uint32_t)__shfl_up((int)x, d, 64);
    if (lane >= d) x += y;
  }
  int wid = tid >> 6;
  if (lane == 63) wsum[wid] = x;
  __syncthreads();
  if (tid == 0) {
    uint32_t a = 0;
    for (int w = 0; w < 16; ++w) { uint32_t t = wsum[w]; wsum[w] = a; a += t; }
  }
  __syncthreads();
  uint32_t run = wsum[wid] + (x - s);
  for (int i = 0; i < chunk; ++i) { uint32_t t = vals[i]; h[base + i] = run; run += t; }
  __syncthreads();
}

// per-seg: remove positives from neg hist, build pos hist, scan both,
// emit COARSE fused neg table {u,v} (NB2), compute positive contributions
// (incl. subtracting the spurious coarse neg-style term pass2neg will add).
// R26: 8-slot MLP G-loops (G<=8192 = list capacity; slots i=tid+k*1024).
// Fixup's emb2 loads + qc persist in registers -> 2nd loop needs no
// list/emb2 gathers. Scalar tail loops preserved for G>8192 (dead).
// R26: XCD-aligned seg decode (batch -> XCD pair, matches hist/pass2neg).
__global__ __launch_bounds__(1024) void k_scanpos(
    const uint2* __restrict__ emb2, const float* __restrict__ seed,
    const float* __restrict__ p05, const uint32_t* __restrict__ list,
    uint32_t* __restrict__ hneg_g, float2* __restrict__ tabN,
    float* __restrict__ lov_out, float* __restrict__ seed_fg)
{
  __shared__ uint32_t hn[NB];
  __shared__ uint32_t hp[NB];
  __shared__ uint32_t wsum[16];
  __shared__ float red[32];
  const int g = blockIdx.x;
  const int xcd = g & 7;
  const int b = xcd >> 1;                       // batch -> XCD pair {2b,2b+1}
  const int seg = b * K_ + (((g >> 3) << 1) | (xcd & 1));  // bijective, 128
  const float* pp = &p05[seg * 16];
  const float Gf = pp[7];
  if (Gf <= 0.f) return;     // pass2neg skips this seg too -> tabN never read
  const float sex = pp[0], sey = pp[1], sez = pp[2];
  const float tx = pp[3], ty = pp[4], tz = pp[5], A = pp[6];
  const int tid = threadIdx.x;
  const int base = b * N_;
  const int G = (int)Gf;
  const uint32_t lo = (uint32_t)(seg << SLOT_SHIFT);
  const float Nnegf = (float)N_ - Gf;

  uint32_t* gn = &hneg_g[seg * NB];
  for (int i = tid; i < NB; i += 1024) { hn[i] = gn[i]; hp[i] = 0; }

  // issue all 8 slot list-loads + emb2 gathers up front (R22 MLP mechanism)
  int nn[8];
#pragma unroll
  for (int k = 0; k < 8; ++k) {
    int i = tid + (k << 10);
    nn[k] = (i < G) ? (int)list[lo + i] : -1;
  }
  uint2 ee[8];
#pragma unroll
  for (int k = 0; k < 8; ++k)
    if (nn[k] >= 0) ee[k] = emb2[base + nn[k]];
  float qcv[8];
  __syncthreads();

  // fixup: move this seg's positives out of hn, into hp
#pragma unroll
  for (int k = 0; k < 8; ++k) {
    if (nn[k] >= 0) {
      float2 xy = unpack_h2(ee[k].x);
      float2 zw = unpack_h2(ee[k].y);
      float qc = quad_qc(xy.x, xy.y, zw.x, sex, sey, sez, tx, ty, tz, A);
      qcv[k] = qc;
      atomicAdd(&hn[__float_as_uint(qc) >> 19], 0xFFFFFFFFu);  // -1
      float p = __expf(-qc);
      float qs = -__logf(1.f - p);   // p==1 -> +inf -> bucket 4080, fine
      atomicAdd(&hp[__float_as_uint(qs) >> 19], 1u);
    }
  }
  for (int i = tid + 8192; i < G; i += 1024) {   // dead in practice
    int n = (int)list[lo + i];
    uint2 e = emb2[base + n];
    float2 xy = unpack_h2(e.x);
    float2 zw = unpack_h2(e.y);
    float qc = quad_qc(xy.x, xy.y, zw.x, sex, sey, sez, tx, ty, tz, A);
    atomicAdd(&hn[__float_as_uint(qc) >> 19], 0xFFFFFFFFu);
    float p = __expf(-qc);
    float qs = -__logf(1.f - p);
    atomicAdd(&hp[__float_as_uint(qs) >> 19], 1u);
  }
  __syncthreads();
  scan_excl(hn, wsum, tid);
  scan_excl(hp, wsum, tid);

  // coarse fused neg table (sampled from fine cumulative scans at even idx)
  float2* tN = &tabN[(size_t)seg * NB2];
  for (int bkt = tid; bkt < NB2; bkt += 1024) {
    float R  = (float)hn[2 * bkt];
    float nn2_ = (bkt < NB2 - 1) ? (float)hn[2 * bkt + 2] : Nnegf;
    float m  = nn2_ - R;
    float pb = (float)hp[2 * bkt];
    float pn = (bkt < NB2 - 1) ? (float)hp[2 * bkt + 2] : Gf;
    float gr = Gf + R;
    float psi2 = 2.f / (gr * (gr + m));
    float u = psi2 * (Gf - pb);
    float v = psi2 * (pn - pb) * (1.f / 1048576.f);
    tN[bkt] = make_float2(u, v);
  }

  // positives' own contributions — issue all 8 seed gathers up front;
  // emb2/qc reused from registers (no list/emb2 re-gather).
  float sdv[8];
#pragma unroll
  for (int k = 0; k < 8; ++k)
    if (nn[k] >= 0) sdv[k] = seed[base + nn[k]];

  float lov = 0.f, sfg = 0.f;
#pragma unroll
  for (int k = 0; k < 8; ++k) {
    if (nn[k] >= 0) {
      float qc = qcv[k];
      float p = __expf(-qc);
      float qs = -__logf(1.f - p);
      uint32_t qb = __float_as_uint(qs);
      uint32_t bk = qb >> 19;
      float frac = (float)(qb & 0x7FFFFu) * (1.f / 524288.f);
      float R  = (float)hn[bk];
      float nnv = (bk < NB - 1) ? (float)hn[bk + 1] : Nnegf;
      float F = R + frac * (nnv - R);
      lov += (2.f - 2.f * p) / (Gf + F);
      float s = fast_sigmoid(sdv[k]);
      float d = s - p;
      sfg += d * d;
      // subtract the spurious COARSE neg-style term (bit-identical to table path)
      uint32_t cb = __float_as_uint(qc);
      uint32_t b2 = cb >> 20;
      float fr = (float)(cb & 0xFFFFFu);
      float R2  = (float)hn[2 * b2];
      float nn2_ = (b2 < NB2 - 1) ? (float)hn[2 * b2 + 2] : Nnegf;
      float m2  = nn2_ - R2;
      float pb2 = (float)hp[2 * b2];
      float pn2 = (b2 < NB2 - 1) ? (float)hp[2 * b2 + 2] : Gf;
      float gr2 = Gf + R2;
      float psi2 = 2.f / (gr2 * (gr2 + m2));
      float u2 = psi2 * (Gf - pb2);
      float v2 = psi2 * (pn2 - pb2) * (1.f / 1048576.f);
      lov -= p * fmaf(-v2, fr, u2);
    }
  }
  for (int i = tid + 8192; i < G; i += 1024) {   // dead in practice
    int n = (int)list[lo + i];
    uint2 e = emb2[base + n];
    float2 xy = unpack_h2(e.x);
    float2 zw = unpack_h2(e.y);
    float qc = quad_qc(xy.x, xy.y, zw.x, sex, sey, sez, tx, ty, tz, A);
    float p = __expf(-qc);
    float qs = -__logf(1.f - p);
    uint32_t qb = __float_as_uint(qs);
    uint32_t bk = qb >> 19;
    float frac = (float)(qb & 0x7FFFFu) * (1.f / 524288.f);
    float R  = (float)hn[bk];
    float nnv = (bk < NB - 1) ? (float)hn[bk + 1] : Nnegf;
    float F = R + frac * (nnv - R);
    lov += (2.f - 2.f * p) / (Gf + F);
    float s = fast_sigmoid(seed[base + n]);
    float d = s - p;
    sfg += d * d;
    uint32_t cb = __float_as_uint(qc);
    uint32_t b2 = cb >> 20;
    float fr = (float)(cb & 0xFFFFFu);
    float R2  = (float)hn[2 * b2];
    float nn2_ = (b2 < NB2 - 1) ? (float)hn[2 * b2 + 2] : Nnegf;
    float m2  = nn2_ - R2;
    float pb2 = (float)hp[2 * b2];
    float pn2 = (b2 < NB2 - 1) ? (float)hp[2 * b2 + 2] : Gf;
    float gr2 = Gf + R2;
    float psi2 = 2.f / (gr2 * (gr2 + m2));
    float u2 = psi2 * (Gf - pb2);
    float v2 = psi2 * (pn2 - pb2) * (1.f / 1048576.f);
    lov -= p * fmaf(-v2, fr, u2);
  }

  for (int d = 32; d > 0; d >>= 1) {
    lov += __shfl_down(lov, d, 64);
    sfg += __shfl_down(sfg, d, 64);
  }
  int wid = tid >> 6, lane = tid & 63;
  if (lane == 0) { red[wid] = lov; red[16 + wid] = sfg; }
  __syncthreads();
  if (tid == 0) {
    float lt = 0.f, st = 0.f;
    for (int w = 0; w < 16; ++w) { lt += red[w]; st += red[16 + w]; }
    atomicAdd(&lov_out[seg], lt);
    atomicAdd(&seed_fg[b], st);
  }
}

// branch-free negative pass — 8B packed emb, 1 seg/block, 256 thr.
// R25: tabN staged in LDS (16KB) — the global gather was ~49 L1 lines/inst.
// Do NOT regroup (R10/R11). NO device-scope fence/atomic epilogue (R14).
// R17: XCD-clustered decode (batch -> XCD pair) for L2-resident emb2.
// R23: 8-pt stripes; launch_bounds(256,8) pins 8 blocks/CU.
__global__ __launch_bounds__(256, 8) void k_pass2neg(
    const uint2* __restrict__ emb2, const float* __restrict__ p05,
    const float2* __restrict__ tabN, float* __restrict__ lov_out)
{
  __shared__ float red[4];
  __shared__ float2 stab[NB2];   // 16 KB
  const int g = blockIdx.x;
  const int xcd = g & 7;
  const int bb = xcd >> 1;                      // batch -> XCD pair {2b,2b+1}
  const int sub = ((g >> 3) << 1) | (xcd & 1);  // 0..511, bijective
  const int seg = bb * K_ + (sub >> 4);
  const int chunk = sub & (S2 - 1);
  const int b = bb;
  const float* pp = &p05[seg * 16];
  const float Gf = pp[7];
  if (Gf <= 0.f) return;                        // block-uniform -> barrier-safe
  const float sex = pp[0], sey = pp[1], sez = pp[2];
  const float tx = pp[3], ty = pp[4], tz = pp[5], A = pp[6];
  const int tid = threadIdx.x;
  const int base = b * N_;
  const int n0 = chunk * (N_ / S2);         // 15625 per chunk
  const int nfull = n0 + 14336;             // 7 full 2048-pt stripes (8/thread)
  const int n1 = n0 + (N_ / S2);
  const float2* tN = &tabN[(size_t)seg * NB2];

  // stage the coarse table (2048 x 8B, coalesced) into LDS
  for (int i = tid; i < NB2; i += 256) stab[i] = tN[i];
  __syncthreads();

  float l0 = 0.f, l1 = 0.f, l2 = 0.f, l3 = 0.f;
  float l4 = 0.f, l5 = 0.f, l6 = 0.f, l7 = 0.f;
  for (int s = n0 + tid; s < nfull; s += 2048) {
    uint2 e0 = emb2[base + s];
    uint2 e1 = emb2[base + s + 256];
    uint2 e2 = emb2[base + s + 512];
    uint2 e3 = emb2[base + s + 768];
    uint2 e4 = emb2[base + s + 1024];
    uint2 e5 = emb2[base + s + 1280];
    uint2 e6 = emb2[base + s + 1536];
    uint2 e7 = emb2[base + s + 1792];
    float2 a0 = unpack_h2(e0.x), b0 = unpack_h2(e0.y);
    float2 a1 = unpack_h2(e1.x), b1 = unpack_h2(e1.y);
    float2 a2 = unpack_h2(e2.x), b2 = unpack_h2(e2.y);
    float2 a3 = unpack_h2(e3.x), b3 = unpack_h2(e3.y);
    float2 a4 = unpack_h2(e4.x), b4 = unpack_h2(e4.y);
    float2 a5 = unpack_h2(e5.x), b5 = unpack_h2(e5.y);
    float2 a6 = unpack_h2(e6.x), b6 = unpack_h2(e6.y);
    float2 a7 = unpack_h2(e7.x), b7 = unpack_h2(e7.y);
    float q0 = quad_qc(a0.x, a0.y, b0.x, sex, sey, sez, tx, ty, tz, A);
    float q1 = quad_qc(a1.x, a1.y, b1.x, sex, sey, sez, tx, ty, tz, A);
    float q2 = quad_qc(a2.x, a2.y, b2.x, sex, sey, sez, tx, ty, tz, A);
    float q3 = quad_qc(a3.x, a3.y, b3.x, sex, sey, sez, tx, ty, tz, A);
    float q4 = quad_qc(a4.x, a4.y, b4.x, sex, sey, sez, tx, ty, tz, A);
    float q5 = quad_qc(a5.x, a5.y, b5.x, sex, sey, sez, tx, ty, tz, A);
    float q6 = quad_qc(a6.x, a6.y, b6.x, sex, sey, sez, tx, ty, tz, A);
    float q7 = quad_qc(a7.x, a7.y, b7.x, sex, sey, sez, tx, ty, tz, A);
    uint32_t c0 = __float_as_uint(q0), c1 = __float_as_uint(q1);
    uint32_t c2 = __float_as_uint(q2), c3 = __float_as_uint(q3);
    uint32_t c4 = __float_as_uint(q4), c5 = __float_as_uint(q5);
    uint32_t c6 = __float_as_uint(q6), c7 = __float_as_uint(q7);
    float2 t0 = stab[c0 >> 20];
    float2 t1 = stab[c1 >> 20];
    float2 t2 = stab[c2 >> 20];
    float2 t3 = stab[c3 >> 20];
    float2 t4 = stab[c4 >> 20];
    float2 t5 = stab[c5 >> 20];
    float2 t6 = stab[c6 >> 20];
    float2 t7 = stab[c7 >> 20];
    float p0 = __expf(-q0), p1 = __expf(-q1);
    float p2 = __expf(-q2), p3 = __expf(-q3);
    float p4 = __expf(-q4), p5 = __expf(-q5);
    float p6 = __expf(-q6), p7 = __expf(-q7);
    l0 = fmaf(p0, fmaf(-t0.y, (float)(c0 & 0xFFFFFu), t0.x), l0);
    l1 = fmaf(p1, fmaf(-t1.y, (float)(c1 & 0xFFFFFu), t1.x), l1);
    l2 = fmaf(p2, fmaf(-t2.y, (float)(c2 & 0xFFFFFu), t2.x), l2);
    l3 = fmaf(p3, fmaf(-t3.y, (float)(c3 & 0xFFFFFu), t3.x), l3);
    l4 = fmaf(p4, fmaf(-t4.y, (float)(c4 & 0xFFFFFu), t4.x), l4);
    l5 = fmaf(p5, fmaf(-t5.y, (float)(c5 & 0xFFFFFu), t5.x), l5);
    l6 = fmaf(p6, fmaf(-t6.y, (float)(c6 & 0xFFFFFu), t6.x), l6);
    l7 = fmaf(p7, fmaf(-t7.y, (float)(c7 & 0xFFFFFu), t7.x), l7);
  }
  for (int n = nfull + tid; n < n1; n += 256) {   // 1289-pt tail
    uint2 e = emb2[base + n];
    float2 xy = unpack_h2(e.x);
    float2 zw = unpack_h2(e.y);
    float qc = quad_qc(xy.x, xy.y, zw.x, sex, sey, sez, tx, ty, tz, A);
    float p = __expf(-qc);
    uint32_t cb = __float_as_uint(qc);
    float2 t = stab[cb >> 20];
    l0 = fmaf(p, fmaf(-t.y, (float)(cb & 0xFFFFFu), t.x), l0);
  }

  float lov = ((l0 + l1) + (l2 + l3)) + ((l4 + l5) + (l6 + l7));
  for (int d = 32; d > 0; d >>= 1) lov += __shfl_down(lov, d, 64);
  int wid = tid >> 6, lane = tid & 63;
  if (lane == 0) red[wid] = lov;
  __syncthreads();
  if (tid == 0) {
    float lt = red[0] + red[1] + red[2] + red[3];
    atomicAdd(&lov_out[seg], lt);
  }
}

__global__ void k_final(const float* __restrict__ p05, const float* __restrict__ lov,
                        const float* __restrict__ seed_bg, const float* __restrict__ seed_fg,
                        float* __restrict__ out)
{
  __shared__ float sv[B_], sl[B_], ss[B_];
  int tid = threadIdx.x;   // 128 threads, one per seg
  if (tid < B_) { sv[tid] = 0.f; sl[tid] = 0.f; ss[tid] = 0.f; }
  __syncthreads();
  int b = tid >> 5;
  float vf = p05[tid * 16 + 8];
  atomicAdd(&sv[b], vf);
  atomicAdd(&sl[b], lov[tid] * vf);
  atomicAdd(&ss[b], p05[tid * 16 + 9] * vf);
  __syncthreads();
  if (tid == 0) {
    float total = 0.f;
    for (int bb = 0; bb < B_; ++bb) {
      float obj = fmaxf(sv[bb], 1.f);
      float seed_l = (seed_bg[bb] + seed_fg[bb]) / (float)N_;
      total += sl[bb] / obj + 10.f * (ss[bb] / obj) + 10.f * seed_l;
    }
    out[0] = total / (float)B_;
  }
}

extern "C" void kernel_launch(void* const* d_in, const int* in_sizes, int n_in,
                              void* d_out, int out_size, void* d_ws, size_t ws_size,
                              hipStream_t stream) {
  const float* off  = (const float*)d_in[0];
  const float* crd  = (const float*)d_in[1];
  const float* sig  = (const float*)d_in[2];
  const float* seed = (const float*)d_in[3];
  const int*   inst = (const int*)d_in[4];

  float* ws      = (float*)d_ws;
  float* acc     = ws;                 // 1024 floats
  float* seed_bg = ws + 1024;          // 4
  float* seed_fg = ws + 1028;          // 4
  float* lov     = ws + 1032;          // 128
  uint32_t* cursor = (uint32_t*)(ws + 1160);  // 128
  float* p05     = ws + 2048;          // byte 8192
  char* pbase = (char*)d_ws;
  uint2*    emb2   = (uint2*)(pbase + 65536);                       // 8 MB half4
  uint32_t* hneg_g = (uint32_t*)(pbase + 65536 + 8388608);          // 2 MB
  float2*   tabN   = (float2*)(pbase + 65536 + 8388608 + 2097152);  // 2 MB coarse
  uint32_t* list   = (uint32_t*)((char*)tabN + 2097152);            // 4 MB

  hipMemsetAsync(d_ws, 0, 8192, stream);   // acc/seed/lov/cursor

  dim3 ge((N_ + 2047) / 2048, B_);   // 123 x 4 — 8 pts/thread (R22: max MLP)
  k_emb<<<ge, 256, 0, stream>>>(off, crd, seed, inst, seed_bg, emb2, cursor, list,
                                hneg_g);
  k_segstats<<<B_ * K_ * SC, 256, 0, stream>>>(emb2, sig, list, cursor, acc);
  k_hist<<<B_ * (K_ / KG) * HCH, 512, 0, stream>>>(emb2, acc, p05, hneg_g);  // 1024, XCD-decoded
  k_scanpos<<<B_ * K_, 1024, 0, stream>>>(emb2, seed, p05, list, hneg_g, tabN, lov, seed_fg);  // 128, XCD-decoded
  k_pass2neg<<<B_ * K_ * S2, 256, 0, stream>>>(emb2, p05, tabN, lov);  // 2048, XCD-decoded
  k_final<<<1, 128, 0, stream>>>(p05, lov, seed_bg, seed_fg, (float*)d_out);
}